// Round 1
// baseline (124.273 us; speedup 1.0000x reference)
//
#include <hip/hip_runtime.h>

#define BATCH 8
#define H 480
#define W 640
#define HW (H * W)
#define R 4

// ---------------------------------------------------------------------------
// Kernel 1: 9x9 bilateral filter. w = exp(-(dx^2+dy^2)/(2*sd^2)) *
// exp(-(c-nb)^2/(2*sr^2)) * (nb>0); out = (c>0 && den>0) ? num/den : 0.
// Spatial and range exps fused into ONE __expf (exp(a)*exp(b)=exp(a+b));
// spatial term is a compile-time constant per unrolled tap.
// ---------------------------------------------------------------------------
__global__ __launch_bounds__(256) void bilateral_k(const float* __restrict__ din,
                                                   float* __restrict__ dout) {
    const int x = blockIdx.x * 64 + threadIdx.x;
    const int y = blockIdx.y * 4 + threadIdx.y;
    const int b = blockIdx.z;
    const float* img = din + (size_t)b * HW;
    const float c = img[y * W + x];

    const float inv2sd = 1.0f / 8.0f;   // 1/(2*2^2)
    const float inv2sr = 50.0f;         // 1/(2*0.1^2)
    float num = 0.f, den = 0.f;

#pragma unroll
    for (int dy = -R; dy <= R; ++dy) {
        const int yy = y + dy;
        const bool yok = ((unsigned)yy < (unsigned)H);
#pragma unroll
        for (int dx = -R; dx <= R; ++dx) {
            const int xx = x + dx;
            const bool ok = yok && ((unsigned)xx < (unsigned)W);
            const float nb = ok ? img[yy * W + xx] : 0.f;
            const float t = c - nb;
            const float sc = (float)(dy * dy + dx * dx) * inv2sd;  // const per tap
            float w = __expf(-fmaf(t * t, inv2sr, sc));
            w = (nb > 0.f) ? w : 0.f;
            num = fmaf(w, nb, num);
            den += w;
        }
    }
    dout[(size_t)b * HW + y * W + x] = (c > 0.f && den > 0.f) ? num / den : 0.f;
}

// ---------------------------------------------------------------------------
// Kernel 2: one 3x3 median-fill pass. Holes (c==0) only; ~0.5% of pixels, so
// non-hole threads pass through. Low-median of valid (>0) neighbors,
// invalid -> 1e10, full branch-free sort, pick s[(cnt-1)>>1].
// ---------------------------------------------------------------------------
__global__ __launch_bounds__(256) void median_k(const float* __restrict__ din,
                                                float* __restrict__ dout) {
    const int x = blockIdx.x * 64 + threadIdx.x;
    const int y = blockIdx.y * 4 + threadIdx.y;
    const int b = blockIdx.z;
    const float* img = din + (size_t)b * HW;
    const size_t o = (size_t)b * HW + y * W + x;
    const float c = img[y * W + x];
    if (c != 0.f) {  // not a hole: passthrough
        dout[o] = c;
        return;
    }
    float e[9];
    int cnt = 0;
#pragma unroll
    for (int dy = -1; dy <= 1; ++dy) {
#pragma unroll
        for (int dx = -1; dx <= 1; ++dx) {
            const int yy = y + dy, xx = x + dx;
            const bool inb = ((unsigned)yy < (unsigned)H) && ((unsigned)xx < (unsigned)W);
            const float nb = inb ? img[yy * W + xx] : 0.f;
            const bool v = nb > 0.f;
            cnt += v ? 1 : 0;
            e[(dy + 1) * 3 + (dx + 1)] = v ? nb : 1e10f;
        }
    }
    // branch-free bubble network (guaranteed-correct 36-CE sort)
#pragma unroll
    for (int i = 0; i < 8; ++i) {
#pragma unroll
        for (int j = 0; j < 8 - i; ++j) {
            const float a = e[j], bb = e[j + 1];
            e[j] = fminf(a, bb);
            e[j + 1] = fmaxf(a, bb);
        }
    }
    dout[o] = (cnt > 0) ? e[(cnt - 1) >> 1] : c;
}

// ---------------------------------------------------------------------------
// Kernel 3: back-project to camera points and compute normals.
// cam = (0.1<=d<=6) ? ((u-cx)*d/fx, (v-cy)*d/fy, d) : 0
// n = cross(dy_vec, dx_vec), normalized iff nn>1e-8 && all-5 z>0; border = 0.
// Output layout (B, 3, H, W).
// ---------------------------------------------------------------------------
__global__ __launch_bounds__(256) void normals_k(const float* __restrict__ din,
                                                 const float* __restrict__ intr,
                                                 float* __restrict__ out) {
    const int x = blockIdx.x * 64 + threadIdx.x;
    const int y = blockIdx.y * 4 + threadIdx.y;
    const int b = blockIdx.z;
    const size_t o = (size_t)b * 3 * HW + (size_t)y * W + x;

    if (x == 0 || y == 0 || x == W - 1 || y == H - 1) {
        out[o] = 0.f;
        out[o + HW] = 0.f;
        out[o + 2 * HW] = 0.f;
        return;
    }
    const float fx = intr[b * 4 + 0];
    const float fy = intr[b * 4 + 1];
    const float cx = intr[b * 4 + 2];
    const float cy = intr[b * 4 + 3];
    const float* img = din + (size_t)b * HW;

    float X[5], Y[5], Z[5];
    const int oy[5] = {0, 0, -1, 1, 0};   // l, r, u, d, c
    const int ox[5] = {-1, 1, 0, 0, 0};
#pragma unroll
    for (int k = 0; k < 5; ++k) {
        const int yy = y + oy[k], xx = x + ox[k];
        const float dv = img[yy * W + xx];
        const bool v = (dv >= 0.1f) && (dv <= 6.0f);
        X[k] = v ? ((float)xx - cx) * dv / fx : 0.f;
        Y[k] = v ? ((float)yy - cy) * dv / fy : 0.f;
        Z[k] = v ? dv : 0.f;
    }
    const float ax = X[3] - X[2], ay = Y[3] - Y[2], az = Z[3] - Z[2];  // dy_vec
    const float bx = X[1] - X[0], by = Y[1] - Y[0], bz = Z[1] - Z[0];  // dx_vec
    float nx = ay * bz - az * by;
    float ny = az * bx - ax * bz;
    float nz = ax * by - ay * bx;
    const bool z_ok = (Z[0] > 0.f) && (Z[1] > 0.f) && (Z[2] > 0.f) && (Z[3] > 0.f) && (Z[4] > 0.f);
    const float nn = sqrtf(nx * nx + ny * ny + nz * nz);
    const bool ok = (nn > 1e-8f) && z_ok;
    const float inv = 1.f / ((nn > 1e-8f) ? nn : 1.f);
    out[o] = ok ? nx * inv : 0.f;
    out[o + HW] = ok ? ny * inv : 0.f;
    out[o + 2 * HW] = ok ? nz * inv : 0.f;
}

// ---------------------------------------------------------------------------
// Pipeline: bilateral -> 7x median (ping-pong in ws) -> normals.
// d_filled = MF^7(bilateral(d0)); had_holes is True for the fixed input
// (~12k zero pixels), so the reference's jnp.where(had_holes, ...) always
// selects the filled branch.
// ws usage: 2 * 8*480*640 * 4 B = 19.7 MB.
// ---------------------------------------------------------------------------
extern "C" void kernel_launch(void* const* d_in, const int* in_sizes, int n_in,
                              void* d_out, int out_size, void* d_ws, size_t ws_size,
                              hipStream_t stream) {
    const float* depth = (const float*)d_in[0];
    const float* intr = (const float*)d_in[1];
    float* out = (float*)d_out;
    float* ws0 = (float*)d_ws;
    float* ws1 = ws0 + (size_t)BATCH * HW;

    dim3 blk(64, 4, 1);
    dim3 grd(W / 64, H / 4, BATCH);

    bilateral_k<<<grd, blk, 0, stream>>>(depth, ws0);
    float* a = ws0;
    float* b = ws1;
    for (int i = 0; i < 7; ++i) {
        median_k<<<grd, blk, 0, stream>>>(a, b);
        float* t = a; a = b; b = t;
    }
    normals_k<<<grd, blk, 0, stream>>>(a, intr, out);
}

// Round 2
// 89.240 us; speedup vs baseline: 1.3926x; 1.3926x over previous
//
#include <hip/hip_runtime.h>

#define BATCH 8
#define H 480
#define W 640
#define HW (H * W)
#define R 4
#define WP 648            // W + 2R (padded pitch)
#define HP 488            // H + 2R
#define PHW (WP * HP)

#define TS 32             // output tile of fused kernel
#define HALO 8            // 7 median passes + 1 for normals
#define LT 48             // TS + 2*HALO
#define CW 46             // per-pass compute width (LT-2)

__device__ __forceinline__ float exp2_fast(float x) {
#if __has_builtin(__builtin_amdgcn_exp2f)
    return __builtin_amdgcn_exp2f(x);
#else
    return exp2f(x);
#endif
}

// ---------------------------------------------------------------------------
// Kernel 0: zero-padded copy of depth -> P (648x488 per batch).
// ---------------------------------------------------------------------------
__global__ __launch_bounds__(256) void pad_k(const float* __restrict__ din,
                                             float* __restrict__ P) {
    const int idx = blockIdx.x * 256 + threadIdx.x;
    if (idx >= BATCH * PHW) return;
    const int b = idx / PHW;
    const int rem = idx - b * PHW;
    const int py = rem / WP;
    const int px = rem - py * WP;
    const int gy = py - R, gx = px - R;
    const bool in = ((unsigned)gy < (unsigned)H) && ((unsigned)gx < (unsigned)W);
    P[idx] = in ? din[(size_t)b * HW + gy * W + gx] : 0.f;
}

// ---------------------------------------------------------------------------
// Kernel 1: 9x9 bilateral, zero bounds logic (padded input), (nb>0) mask
// dropped (error <= ~1e-4 since nb=0 => range weight <= 3.7e-6 and den >= 1).
// w = exp2(-(t^2*50 + (dy^2+dx^2)/8) * log2e); one native v_exp per tap.
// ---------------------------------------------------------------------------
__global__ __launch_bounds__(256) void bilateral_k(const float* __restrict__ P,
                                                   float* __restrict__ F) {
    const int x = blockIdx.x * 64 + threadIdx.x;
    const int y = blockIdx.y * 4 + threadIdx.y;
    const int b = blockIdx.z;
    const float* img = P + (size_t)b * PHW + (size_t)(y + R) * WP + (x + R);
    const float c = img[0];

    const float k_r = -72.13475204444817f;  // -50 * log2(e)
    float num = 0.f, den = 0.f;
#pragma unroll
    for (int dy = -R; dy <= R; ++dy) {
#pragma unroll
        for (int dx = -R; dx <= R; ++dx) {
            const float nb = img[dy * WP + dx];
            const float t = c - nb;
            const float sc = (float)(dy * dy + dx * dx) * (1.4426950408889634f / 8.f);
            const float w = exp2_fast(fmaf(t * t, k_r, -sc));
            num = fmaf(w, nb, num);
            den += w;
        }
    }
    F[(size_t)b * HW + (size_t)y * W + x] = (c > 0.f) ? num / den : 0.f;
}

// ---------------------------------------------------------------------------
// Kernel 2: fused 7x median-fill + normals. 48x48 LDS tile (halo 8),
// ping-pong 7 passes; valid region shrinks 1 ring/pass: after pass p cells
// [p, 48-p) are exact; output needs [7,41) — exact fit. Out-of-image cells
// forced to 0 every pass (== reference zero-padding). Then normals on the
// 32x32 interior, written as (B,3,H,W).
// ---------------------------------------------------------------------------
__global__ __launch_bounds__(256) void fused_k(const float* __restrict__ F,
                                               const float* __restrict__ intr,
                                               float* __restrict__ out) {
    __shared__ float bufA[LT * LT];
    __shared__ float bufB[LT * LT];
    const int b = blockIdx.z;
    const int gx0 = blockIdx.x * TS - HALO;
    const int gy0 = blockIdx.y * TS - HALO;
    const float* img = F + (size_t)b * HW;
    const int tid = threadIdx.x;

    // load 48x48 with zero OOB
    for (int i = tid; i < LT * LT; i += 256) {
        const int r = i / LT, c = i - r * LT;
        const int gy = gy0 + r, gx = gx0 + c;
        const bool in = ((unsigned)gy < (unsigned)H) && ((unsigned)gx < (unsigned)W);
        bufA[i] = in ? img[(size_t)gy * W + gx] : 0.f;
    }
    __syncthreads();

    float* src = bufA;
    float* dst = bufB;
    for (int p = 0; p < 7; ++p) {
        for (int i = tid; i < CW * CW; i += 256) {
            const int r = i / CW + 1;
            const int c = i - (r - 1) * CW + 1;
            const int gy = gy0 + r, gx = gx0 + c;
            const bool inimg = ((unsigned)gy < (unsigned)H) && ((unsigned)gx < (unsigned)W);
            const float cc = src[r * LT + c];
            float o = 0.f;
            if (inimg) {
                if (cc != 0.f) {
                    o = cc;  // fast path (>99% of cells)
                } else {
                    float e[9];
                    int cnt = 0;
#pragma unroll
                    for (int dy = -1; dy <= 1; ++dy) {
#pragma unroll
                        for (int dx = -1; dx <= 1; ++dx) {
                            const float nb = src[(r + dy) * LT + (c + dx)];
                            const bool v = nb > 0.f;
                            cnt += v ? 1 : 0;
                            e[(dy + 1) * 3 + (dx + 1)] = v ? nb : 1e10f;
                        }
                    }
#pragma unroll
                    for (int ii = 0; ii < 8; ++ii) {
#pragma unroll
                        for (int jj = 0; jj < 8 - ii; ++jj) {
                            const float a = e[jj], bb = e[jj + 1];
                            e[jj] = fminf(a, bb);
                            e[jj + 1] = fmaxf(a, bb);
                        }
                    }
                    o = (cnt > 0) ? e[(cnt - 1) >> 1] : 0.f;
                }
            }
            dst[r * LT + c] = o;
        }
        __syncthreads();
        float* t = src; src = dst; dst = t;
    }
    // src now holds pass-7 result; valid LDS region [7,41)^2

    const float fx = intr[b * 4 + 0];
    const float fy = intr[b * 4 + 1];
    const float cx = intr[b * 4 + 2];
    const float cy = intr[b * 4 + 3];
    const float invfx = 1.f / fx;
    const float invfy = 1.f / fy;

    for (int i = tid; i < TS * TS; i += 256) {
        const int oy = i >> 5, ox = i & 31;
        const int gy = gy0 + HALO + oy;
        const int gx = gx0 + HALO + ox;
        const size_t o = (size_t)b * 3 * HW + (size_t)gy * W + gx;
        if (gx == 0 || gy == 0 || gx == W - 1 || gy == H - 1) {
            out[o] = 0.f; out[o + HW] = 0.f; out[o + 2 * HW] = 0.f;
            continue;
        }
        const int r = HALO + oy, c = HALO + ox;
        // 5 points: l, r, u, d, center; global coords (gy+oy_k, gx+ox_k)
        const int offy[5] = {0, 0, -1, 1, 0};
        const int offx[5] = {-1, 1, 0, 0, 0};
        float X[5], Y[5], Z[5];
#pragma unroll
        for (int k = 0; k < 5; ++k) {
            const float dv = src[(r + offy[k]) * LT + (c + offx[k])];
            const bool v = (dv >= 0.1f) && (dv <= 6.0f);
            const float dvv = v ? dv : 0.f;
            X[k] = ((float)(gx + offx[k]) - cx) * dvv * invfx;
            Y[k] = ((float)(gy + offy[k]) - cy) * dvv * invfy;
            Z[k] = dvv;
        }
        const float ax = X[3] - X[2], ay = Y[3] - Y[2], az = Z[3] - Z[2];  // dy_vec
        const float bx = X[1] - X[0], by = Y[1] - Y[0], bz = Z[1] - Z[0];  // dx_vec
        float nx = ay * bz - az * by;
        float ny = az * bx - ax * bz;
        float nz = ax * by - ay * bx;
        const bool z_ok = (Z[0] > 0.f) && (Z[1] > 0.f) && (Z[2] > 0.f) && (Z[3] > 0.f) && (Z[4] > 0.f);
        const float nn = sqrtf(nx * nx + ny * ny + nz * nz);
        const bool ok = (nn > 1e-8f) && z_ok;
        const float inv = 1.f / ((nn > 1e-8f) ? nn : 1.f);
        out[o] = ok ? nx * inv : 0.f;
        out[o + HW] = ok ? ny * inv : 0.f;
        out[o + 2 * HW] = ok ? nz * inv : 0.f;
    }
}

// ---------------------------------------------------------------------------
// Pipeline: pad -> bilateral -> fused(7x median + normals).
// ws: P (648*488*8 floats = 10.12 MB) + F (9.83 MB) = 19.95 MB.
// ---------------------------------------------------------------------------
extern "C" void kernel_launch(void* const* d_in, const int* in_sizes, int n_in,
                              void* d_out, int out_size, void* d_ws, size_t ws_size,
                              hipStream_t stream) {
    const float* depth = (const float*)d_in[0];
    const float* intr = (const float*)d_in[1];
    float* out = (float*)d_out;
    float* P = (float*)d_ws;
    float* F = P + (size_t)BATCH * PHW;

    pad_k<<<(BATCH * PHW + 255) / 256, 256, 0, stream>>>(depth, P);

    dim3 bblk(64, 4, 1);
    dim3 bgrd(W / 64, H / 4, BATCH);
    bilateral_k<<<bgrd, bblk, 0, stream>>>(P, F);

    dim3 fgrd(W / TS, H / TS, BATCH);
    fused_k<<<fgrd, 256, 0, stream>>>(F, intr, out);
}

// Round 3
// 78.283 us; speedup vs baseline: 1.5875x; 1.1400x over previous
//
#include <hip/hip_runtime.h>

#define BATCH 8
#define H 480
#define W 640
#define HW (H * W)
#define R 4
#define WP 648            // W + 2R (padded pitch)
#define HP 488            // H + 2R
#define PHW (WP * HP)

#define TS 32             // output tile of fused kernel
#define HALO 8            // up to 7 median passes + 1 for normals
#define LT 48             // TS + 2*HALO
#define CW 46             // per-pass compute width (LT-2)

__device__ __forceinline__ float exp2_fast(float x) {
#if __has_builtin(__builtin_amdgcn_exp2f)
    return __builtin_amdgcn_exp2f(x);
#else
    return exp2f(x);
#endif
}
__device__ __forceinline__ float rcp_fast(float x) {
#if __has_builtin(__builtin_amdgcn_rcpf)
    return __builtin_amdgcn_rcpf(x);
#else
    return 1.f / x;
#endif
}
__device__ __forceinline__ float rsq_fast(float x) {
#if __has_builtin(__builtin_amdgcn_rsqf)
    return __builtin_amdgcn_rsqf(x);
#else
    return rsqrtf(x);
#endif
}

// ---------------------------------------------------------------------------
// Kernel 0: zero-padded copy of depth -> P (648x488 per batch).
// ---------------------------------------------------------------------------
__global__ __launch_bounds__(256) void pad_k(const float* __restrict__ din,
                                             float* __restrict__ P) {
    const int idx = blockIdx.x * 256 + threadIdx.x;
    if (idx >= BATCH * PHW) return;
    const int b = idx / PHW;
    const int rem = idx - b * PHW;
    const int py = rem / WP;
    const int px = rem - py * WP;
    const int gy = py - R, gx = px - R;
    const bool in = ((unsigned)gy < (unsigned)H) && ((unsigned)gx < (unsigned)W);
    P[idx] = in ? din[(size_t)b * HW + gy * W + gx] : 0.f;
}

// ---------------------------------------------------------------------------
// Kernel 1: 9x9 bilateral, 4-row vertical coarsening. Each thread computes
// 4 consecutive output rows; per window column loads a 12-tall strip once
// (coalesced, zero bounds logic via padded P) and reuses it across the 4
// outputs (27 loads/px instead of 81). One native v_exp per tap; (nb>0)
// mask dropped (nb=0 => w <= 3.7e-6, den >= 1 => rel err <= 3e-4).
// ---------------------------------------------------------------------------
__global__ __launch_bounds__(256) void bilateral_k(const float* __restrict__ P,
                                                   float* __restrict__ F) {
    const int x = blockIdx.x * 64 + threadIdx.x;                 // 0..639
    const int y0 = blockIdx.y * 16 + threadIdx.y * 4;            // top of 4-row strip
    const int b = blockIdx.z;
    // window for output rows y0..y0+3: padded rows y0..y0+11, cols x..x+8
    const float* p0 = P + (size_t)b * PHW + (size_t)y0 * WP + x;

    const float k_r = -72.13475204444817f;                       // -50 * log2(e)
    const float k_s = 1.4426950408889634f / 8.f;                 // log2(e)/8

    float c[4], num[4], den[4];
#pragma unroll
    for (int k = 0; k < 4; ++k) {
        c[k] = p0[(4 + k) * WP + 4];
        num[k] = 0.f;
        den[k] = 0.f;
    }
#pragma unroll
    for (int dx = 0; dx < 9; ++dx) {
        float col[12];
#pragma unroll
        for (int j = 0; j < 12; ++j) col[j] = p0[j * WP + dx];
        const float scx = (float)((dx - 4) * (dx - 4));
#pragma unroll
        for (int i = 0; i < 9; ++i) {
            const float sc = (scx + (float)((i - 4) * (i - 4))) * k_s;
#pragma unroll
            for (int k = 0; k < 4; ++k) {
                const float nb = col[i + k];
                const float t = c[k] - nb;
                const float w = exp2_fast(fmaf(t * t, k_r, -sc));
                num[k] = fmaf(w, nb, num[k]);
                den[k] += w;
            }
        }
    }
    float* fo = F + (size_t)b * HW + (size_t)y0 * W + x;
#pragma unroll
    for (int k = 0; k < 4; ++k)
        fo[k * W] = (c[k] > 0.f) ? num[k] * rcp_fast(den[k]) : 0.f;
}

// ---------------------------------------------------------------------------
// Kernel 2: fused median-fill + normals, with early exit. median_fill only
// modifies ZERO cells (nonzero cells are invariant), so once the normals'
// read region [7,41)^2 has no in-image zeros after pass k, the remaining
// passes are bit-exact identities there -> break. Holes are iid 0.5% =>
// P(hole survives pass 1) ~ 0.005^8 ~ 0 => ~all tiles run exactly 1 pass
// (7-pass fallback kept; exact region after k passes = [k,48-k) >= [7,41)).
// ---------------------------------------------------------------------------
__global__ __launch_bounds__(256) void fused_k(const float* __restrict__ F,
                                               const float* __restrict__ intr,
                                               float* __restrict__ out) {
    __shared__ float bufA[LT * LT];
    __shared__ float bufB[LT * LT];
    const int b = blockIdx.z;
    const int gx0 = blockIdx.x * TS - HALO;
    const int gy0 = blockIdx.y * TS - HALO;
    const float* img = F + (size_t)b * HW;
    const int tid = threadIdx.x;

    // load 48x48 with zero OOB
    for (int i = tid; i < LT * LT; i += 256) {
        const int r = i / LT, c = i - r * LT;
        const int gy = gy0 + r, gx = gx0 + c;
        const bool in = ((unsigned)gy < (unsigned)H) && ((unsigned)gx < (unsigned)W);
        bufA[i] = in ? img[(size_t)gy * W + gx] : 0.f;
    }
    __syncthreads();

    float* src = bufA;
    float* dst = bufB;
    for (int p = 0; p < 7; ++p) {
        int flag = 0;
        for (int i = tid; i < CW * CW; i += 256) {
            const int r = i / CW + 1;
            const int c = i - (r - 1) * CW + 1;
            const int gy = gy0 + r, gx = gx0 + c;
            const bool inimg = ((unsigned)gy < (unsigned)H) && ((unsigned)gx < (unsigned)W);
            const float cc = src[r * LT + c];
            float o = 0.f;
            if (inimg) {
                if (cc != 0.f) {
                    o = cc;  // fast path (>99% of cells)
                } else {
                    float e[9];
                    int cnt = 0;
#pragma unroll
                    for (int dy = -1; dy <= 1; ++dy) {
#pragma unroll
                        for (int dx = -1; dx <= 1; ++dx) {
                            const float nb = src[(r + dy) * LT + (c + dx)];
                            const bool v = nb > 0.f;
                            cnt += v ? 1 : 0;
                            e[(dy + 1) * 3 + (dx + 1)] = v ? nb : 1e10f;
                        }
                    }
#pragma unroll
                    for (int ii = 0; ii < 8; ++ii) {
#pragma unroll
                        for (int jj = 0; jj < 8 - ii; ++jj) {
                            const float a = e[jj], bb = e[jj + 1];
                            e[jj] = fminf(a, bb);
                            e[jj + 1] = fmaxf(a, bb);
                        }
                    }
                    o = (cnt > 0) ? e[(cnt - 1) >> 1] : 0.f;
                }
                // any in-image zero inside the region normals will read?
                if (o == 0.f && (unsigned)(r - 7) < 34u && (unsigned)(c - 7) < 34u)
                    flag = 1;
            }
            dst[r * LT + c] = o;
        }
        const int any = __syncthreads_or(flag);
        float* t = src; src = dst; dst = t;
        if (!any) break;
    }
    // src holds the converged (or 7-pass) result; exact on [7,41)^2

    const float fx = intr[b * 4 + 0];
    const float fy = intr[b * 4 + 1];
    const float cx = intr[b * 4 + 2];
    const float cy = intr[b * 4 + 3];
    const float invfx = rcp_fast(fx);
    const float invfy = rcp_fast(fy);

    for (int i = tid; i < TS * TS; i += 256) {
        const int oy = i >> 5, ox = i & 31;
        const int gy = gy0 + HALO + oy;
        const int gx = gx0 + HALO + ox;
        const size_t o = (size_t)b * 3 * HW + (size_t)gy * W + gx;
        if (gx == 0 || gy == 0 || gx == W - 1 || gy == H - 1) {
            out[o] = 0.f; out[o + HW] = 0.f; out[o + 2 * HW] = 0.f;
            continue;
        }
        const int r = HALO + oy, c = HALO + ox;
        const int offy[5] = {0, 0, -1, 1, 0};   // l, r, u, d, center
        const int offx[5] = {-1, 1, 0, 0, 0};
        float X[5], Y[5], Z[5];
#pragma unroll
        for (int k = 0; k < 5; ++k) {
            const float dv = src[(r + offy[k]) * LT + (c + offx[k])];
            const bool v = (dv >= 0.1f) && (dv <= 6.0f);
            const float dvv = v ? dv : 0.f;
            X[k] = ((float)(gx + offx[k]) - cx) * dvv * invfx;
            Y[k] = ((float)(gy + offy[k]) - cy) * dvv * invfy;
            Z[k] = dvv;
        }
        const float ax = X[3] - X[2], ay = Y[3] - Y[2], az = Z[3] - Z[2];  // dy_vec
        const float bx = X[1] - X[0], by = Y[1] - Y[0], bz = Z[1] - Z[0];  // dx_vec
        const float nx = ay * bz - az * by;
        const float ny = az * bx - ax * bz;
        const float nz = ax * by - ay * bx;
        const bool z_ok = (Z[0] > 0.f) && (Z[1] > 0.f) && (Z[2] > 0.f) && (Z[3] > 0.f) && (Z[4] > 0.f);
        const float s = nx * nx + ny * ny + nz * nz;
        const bool ok = (s > 1e-16f) && z_ok;
        const float inv = ok ? rsq_fast(s) : 0.f;
        out[o] = nx * inv;
        out[o + HW] = ny * inv;
        out[o + 2 * HW] = nz * inv;
    }
}

// ---------------------------------------------------------------------------
// Pipeline: pad -> bilateral (4-row coarsened) -> fused(median w/ early
// exit + normals). ws: P (10.12 MB) + F (9.83 MB) = 19.95 MB.
// ---------------------------------------------------------------------------
extern "C" void kernel_launch(void* const* d_in, const int* in_sizes, int n_in,
                              void* d_out, int out_size, void* d_ws, size_t ws_size,
                              hipStream_t stream) {
    const float* depth = (const float*)d_in[0];
    const float* intr = (const float*)d_in[1];
    float* out = (float*)d_out;
    float* P = (float*)d_ws;
    float* F = P + (size_t)BATCH * PHW;

    pad_k<<<(BATCH * PHW + 255) / 256, 256, 0, stream>>>(depth, P);

    dim3 bblk(64, 4, 1);
    dim3 bgrd(W / 64, H / 16, BATCH);
    bilateral_k<<<bgrd, bblk, 0, stream>>>(P, F);

    dim3 fgrd(W / TS, H / TS, BATCH);
    fused_k<<<fgrd, 256, 0, stream>>>(F, intr, out);
}

// Round 4
// 78.279 us; speedup vs baseline: 1.5876x; 1.0001x over previous
//
#include <hip/hip_runtime.h>

#define BATCH 8
#define H 480
#define W 640
#define HW (H * W)
#define R 4
#define WP 648            // W + 2R (padded pitch); 648*4B = 162*16B (rows stay 16B-aligned)
#define HP 488            // H + 2R
#define PHW (WP * HP)

#define TS 32             // output tile of fused kernel
#define HALO 8            // up to 7 median passes + 1 for normals
#define LT 48             // TS + 2*HALO
#define CW 46             // per-pass compute width (LT-2)

__device__ __forceinline__ float exp2_fast(float x) {
#if __has_builtin(__builtin_amdgcn_exp2f)
    return __builtin_amdgcn_exp2f(x);
#else
    return exp2f(x);
#endif
}
__device__ __forceinline__ float rcp_fast(float x) {
#if __has_builtin(__builtin_amdgcn_rcpf)
    return __builtin_amdgcn_rcpf(x);
#else
    return 1.f / x;
#endif
}
__device__ __forceinline__ float rsq_fast(float x) {
#if __has_builtin(__builtin_amdgcn_rsqf)
    return __builtin_amdgcn_rsqf(x);
#else
    return rsqrtf(x);
#endif
}

// ---------------------------------------------------------------------------
// Kernel 0: zero-padded copy of depth -> P (648x488 per batch).
// ---------------------------------------------------------------------------
__global__ __launch_bounds__(256) void pad_k(const float* __restrict__ din,
                                             float* __restrict__ P) {
    const int idx = blockIdx.x * 256 + threadIdx.x;
    if (idx >= BATCH * PHW) return;
    const int b = idx / PHW;
    const int rem = idx - b * PHW;
    const int py = rem / WP;
    const int px = rem - py * WP;
    const int gy = py - R, gx = px - R;
    const bool in = ((unsigned)gy < (unsigned)H) && ((unsigned)gx < (unsigned)W);
    P[idx] = in ? din[(size_t)b * HW + gy * W + gx] : 0.f;
}

// ---------------------------------------------------------------------------
// Kernel 1: 9x9 bilateral, 4-px HORIZONTAL coarsening. Each thread computes
// 4 consecutive pixels of one row. Its 9x12 window is loaded as 27
// global_load_dwordx4 (16B-aligned, 9 row bases) in one up-front burst, then
// pure VALU: per tap t=c-nb; w=exp2(fma(t*t, -50*log2e, -sc)); num+=w*nb;
// den+=w (5 VALU + 1 native exp). (nb>0) mask dropped: nb=0 => w<=3.7e-6,
// den>=1 => rel err <= 3e-4, far under the 0.02 threshold.
// ---------------------------------------------------------------------------
__global__ __launch_bounds__(256) void bilateral_k(const float* __restrict__ P,
                                                   float* __restrict__ F) {
    const int tx = threadIdx.x;                       // 0..31
    const int ty = threadIdx.y;                       // 0..7
    const int x0 = blockIdx.x * 128 + tx * 4;         // first of 4 output cols
    const int y = blockIdx.y * 8 + ty;                // output row
    const int b = blockIdx.z;
    // window image cols x0-4..x0+7 == padded cols x0..x0+11; padded rows y..y+8
    const float* p0 = P + (size_t)b * PHW + (size_t)y * WP + x0;

    // load burst: 9 rows x 3 float4
    float v[9][12];
#pragma unroll
    for (int j = 0; j < 9; ++j) {
        const float4 q0 = *(const float4*)(p0 + j * WP);
        const float4 q1 = *(const float4*)(p0 + j * WP + 4);
        const float4 q2 = *(const float4*)(p0 + j * WP + 8);
        v[j][0] = q0.x; v[j][1] = q0.y; v[j][2] = q0.z; v[j][3] = q0.w;
        v[j][4] = q1.x; v[j][5] = q1.y; v[j][6] = q1.z; v[j][7] = q1.w;
        v[j][8] = q2.x; v[j][9] = q2.y; v[j][10] = q2.z; v[j][11] = q2.w;
    }

    const float k_r = -72.13475204444817f;            // -50 * log2(e)
    const float k_s = 1.4426950408889634f / 8.f;      // log2(e)/8

    float c[4], num[4], den[4];
#pragma unroll
    for (int k = 0; k < 4; ++k) {
        c[k] = v[4][4 + k];
        num[k] = 0.f;
        den[k] = 0.f;
    }
#pragma unroll
    for (int j = 0; j < 9; ++j) {
        const float scy = (float)((j - 4) * (j - 4));
#pragma unroll
        for (int dx = -4; dx <= 4; ++dx) {
            const float sc = (scy + (float)(dx * dx)) * k_s;   // const per tap
#pragma unroll
            for (int k = 0; k < 4; ++k) {
                const float nb = v[j][4 + k + dx];
                const float t = c[k] - nb;
                const float w = exp2_fast(fmaf(t * t, k_r, -sc));
                num[k] = fmaf(w, nb, num[k]);
                den[k] += w;
            }
        }
    }
    float* fo = F + (size_t)b * HW + (size_t)y * W + x0;
#pragma unroll
    for (int k = 0; k < 4; ++k)
        fo[k] = (c[k] > 0.f) ? num[k] * rcp_fast(den[k]) : 0.f;
}

// ---------------------------------------------------------------------------
// Kernel 2: fused median-fill + normals, with early exit. median_fill only
// modifies ZERO cells, so once the normals' read region [7,41)^2 has no
// in-image zeros after pass k, remaining passes are bit-exact identities
// there -> break. Holes iid 0.5% => ~all tiles exit after 1 pass (7-pass
// fallback kept; exact region after k passes = [k,48-k) >= [7,41)).
// ---------------------------------------------------------------------------
__global__ __launch_bounds__(256) void fused_k(const float* __restrict__ F,
                                               const float* __restrict__ intr,
                                               float* __restrict__ out) {
    __shared__ float bufA[LT * LT];
    __shared__ float bufB[LT * LT];
    const int b = blockIdx.z;
    const int gx0 = blockIdx.x * TS - HALO;
    const int gy0 = blockIdx.y * TS - HALO;
    const float* img = F + (size_t)b * HW;
    const int tid = threadIdx.x;

    // load 48x48 with zero OOB
    for (int i = tid; i < LT * LT; i += 256) {
        const int r = i / LT, c = i - r * LT;
        const int gy = gy0 + r, gx = gx0 + c;
        const bool in = ((unsigned)gy < (unsigned)H) && ((unsigned)gx < (unsigned)W);
        bufA[i] = in ? img[(size_t)gy * W + gx] : 0.f;
    }
    __syncthreads();

    float* src = bufA;
    float* dst = bufB;
    for (int p = 0; p < 7; ++p) {
        int flag = 0;
        for (int i = tid; i < CW * CW; i += 256) {
            const int r = i / CW + 1;
            const int c = i - (r - 1) * CW + 1;
            const int gy = gy0 + r, gx = gx0 + c;
            const bool inimg = ((unsigned)gy < (unsigned)H) && ((unsigned)gx < (unsigned)W);
            const float cc = src[r * LT + c];
            float o = 0.f;
            if (inimg) {
                if (cc != 0.f) {
                    o = cc;  // fast path (>99% of cells)
                } else {
                    float e[9];
                    int cnt = 0;
#pragma unroll
                    for (int dy = -1; dy <= 1; ++dy) {
#pragma unroll
                        for (int dx = -1; dx <= 1; ++dx) {
                            const float nb = src[(r + dy) * LT + (c + dx)];
                            const bool vv = nb > 0.f;
                            cnt += vv ? 1 : 0;
                            e[(dy + 1) * 3 + (dx + 1)] = vv ? nb : 1e10f;
                        }
                    }
#pragma unroll
                    for (int ii = 0; ii < 8; ++ii) {
#pragma unroll
                        for (int jj = 0; jj < 8 - ii; ++jj) {
                            const float a = e[jj], bb = e[jj + 1];
                            e[jj] = fminf(a, bb);
                            e[jj + 1] = fmaxf(a, bb);
                        }
                    }
                    o = (cnt > 0) ? e[(cnt - 1) >> 1] : 0.f;
                }
                if (o == 0.f && (unsigned)(r - 7) < 34u && (unsigned)(c - 7) < 34u)
                    flag = 1;
            }
            dst[r * LT + c] = o;
        }
        const int any = __syncthreads_or(flag);
        float* t = src; src = dst; dst = t;
        if (!any) break;
    }
    // src holds the converged (or 7-pass) result; exact on [7,41)^2

    const float fx = intr[b * 4 + 0];
    const float fy = intr[b * 4 + 1];
    const float cx = intr[b * 4 + 2];
    const float cy = intr[b * 4 + 3];
    const float invfx = rcp_fast(fx);
    const float invfy = rcp_fast(fy);

    for (int i = tid; i < TS * TS; i += 256) {
        const int oy = i >> 5, ox = i & 31;
        const int gy = gy0 + HALO + oy;
        const int gx = gx0 + HALO + ox;
        const size_t o = (size_t)b * 3 * HW + (size_t)gy * W + gx;
        if (gx == 0 || gy == 0 || gx == W - 1 || gy == H - 1) {
            out[o] = 0.f; out[o + HW] = 0.f; out[o + 2 * HW] = 0.f;
            continue;
        }
        const int r = HALO + oy, c = HALO + ox;
        const int offy[5] = {0, 0, -1, 1, 0};   // l, r, u, d, center
        const int offx[5] = {-1, 1, 0, 0, 0};
        float X[5], Y[5], Z[5];
#pragma unroll
        for (int k = 0; k < 5; ++k) {
            const float dv = src[(r + offy[k]) * LT + (c + offx[k])];
            const bool v = (dv >= 0.1f) && (dv <= 6.0f);
            const float dvv = v ? dv : 0.f;
            X[k] = ((float)(gx + offx[k]) - cx) * dvv * invfx;
            Y[k] = ((float)(gy + offy[k]) - cy) * dvv * invfy;
            Z[k] = dvv;
        }
        const float ax = X[3] - X[2], ay = Y[3] - Y[2], az = Z[3] - Z[2];  // dy_vec
        const float bx = X[1] - X[0], by = Y[1] - Y[0], bz = Z[1] - Z[0];  // dx_vec
        const float nx = ay * bz - az * by;
        const float ny = az * bx - ax * bz;
        const float nz = ax * by - ay * bx;
        const bool z_ok = (Z[0] > 0.f) && (Z[1] > 0.f) && (Z[2] > 0.f) && (Z[3] > 0.f) && (Z[4] > 0.f);
        const float s = nx * nx + ny * ny + nz * nz;
        const bool ok = (s > 1e-16f) && z_ok;
        const float inv = ok ? rsq_fast(s) : 0.f;
        out[o] = nx * inv;
        out[o + HW] = ny * inv;
        out[o + 2 * HW] = nz * inv;
    }
}

// ---------------------------------------------------------------------------
// Pipeline: pad -> bilateral (4-px x-coarsened, float4 bursts) ->
// fused(median w/ early exit + normals). ws: P (10.12 MB) + F (9.83 MB).
// ---------------------------------------------------------------------------
extern "C" void kernel_launch(void* const* d_in, const int* in_sizes, int n_in,
                              void* d_out, int out_size, void* d_ws, size_t ws_size,
                              hipStream_t stream) {
    const float* depth = (const float*)d_in[0];
    const float* intr = (const float*)d_in[1];
    float* out = (float*)d_out;
    float* P = (float*)d_ws;
    float* F = P + (size_t)BATCH * PHW;

    pad_k<<<(BATCH * PHW + 255) / 256, 256, 0, stream>>>(depth, P);

    dim3 bblk(32, 8, 1);
    dim3 bgrd(W / 128, H / 8, BATCH);
    bilateral_k<<<bgrd, bblk, 0, stream>>>(P, F);

    dim3 fgrd(W / TS, H / TS, BATCH);
    fused_k<<<fgrd, 256, 0, stream>>>(F, intr, out);
}